// Round 1
// baseline (804.543 us; speedup 1.0000x reference)
//
#include <hip/hip_runtime.h>

// TriPlanePC2Encoder: scatter-mean of point features onto 3 canonical planes.
// B=8, N=200000, C=32, R=128. out[b, plane, c, row, col], plane order xy,yz,xz.
//
// Round 6: counting-sort pipeline, simplified offsets + MLP-maximized gather.
//   bin -> count (LDS hist + global atomic flush into tot) -> scan (exclusive
//   scan per bp into cur) -> reorder (global atomicAdd cursors; cur becomes
//   the INCLUSIVE scan) -> transpose (feat -> point-major bf16) -> gather
//   (one LANE per bin; 32-channel register accumulation; 2-point unroll =>
//   8 outstanding 16B loads/lane; coalesced channel-strided stores).
// ws overlay: bins/tot (first ~11.2MB) are dead before transpose runs, so
// ftT (102.4MB) overlays them. WS_NEED = 123.2MB (proven in prior rounds).

constexpr int R     = 128;
constexpr int NBINS = R * R;        // 16384
constexpr int NPTS  = 200000;
constexpr int NB    = 8;
constexpr int NC    = 32;
constexpr int SPLIT = 16;           // tiles per (b,plane) for count/reorder
constexpr int TILE  = NPTS / SPLIT; // 12500

// ws layout:
//  phase1 (dead after scan/reorder, overlaid by ftT later):
//    bins u16 [3][NB][NPTS]        @ 0           (9,600,000)
//    tot  u32 [24][NBINS]          @ 9,600,000   (1,572,864)   end 11,172,864
//  phase2: ftT bf16 [NB][NPTS][NC] @ 0           (102,400,000)
//  persistent tail:
//    cur  u32 [24][NBINS]          @ 102,400,000 (1,572,864)  excl->incl scan
//    S    u32 [24][NPTS]           @ 103,972,864 (19,200,000)  end 123,172,864
constexpr size_t OFF_TOT = 9600000;
constexpr size_t OFF_CUR = 102400000;
constexpr size_t OFF_S   = 103972864;
constexpr size_t WS_NEED = 123172864;

__device__ __forceinline__ int coord_bin(float p) {
    // xyz_norm = (p+1)/2 - 0.5 ; then /(1+eps) + 0.5 ; clip ; *R ; trunc
    float v = (p + 1.0f) * 0.5f - 0.5f;
    float t = v / 1.00001f + 0.5f;                     // IEEE fp32 divide
    t = fminf(fmaxf(t, 0.0f), (float)(1.0 - 1e-5));
    return (int)(t * 128.0f);
}

__global__ __launch_bounds__(256) void bin_kernel(
    const float* __restrict__ xyz, unsigned short* __restrict__ bins) {
    int i = blockIdx.x * 256 + threadIdx.x;            // over B*N
    if (i >= NB * NPTS) return;
    float x = xyz[3 * (size_t)i + 0];
    float y = xyz[3 * (size_t)i + 1];
    float z = xyz[3 * (size_t)i + 2];
    int ix = coord_bin(x), iy = coord_bin(y), iz = coord_bin(z);
    // plane dims: xy=(0,1) yz=(1,2) xz=(0,2); lin = idx_d0 + R*idx_d1
    bins[0 * (size_t)NB * NPTS + i] = (unsigned short)(ix + R * iy);
    bins[1 * (size_t)NB * NPTS + i] = (unsigned short)(iy + R * iz);
    bins[2 * (size_t)NB * NPTS + i] = (unsigned short)(ix + R * iz);
}

// Per-(bp,split) LDS histogram, flushed into global tot[bp][bin] atomically.
__global__ __launch_bounds__(1024) void count_kernel(
    const unsigned short* __restrict__ bins, unsigned* __restrict__ tot) {
    __shared__ unsigned hist[NBINS];
    int blk   = blockIdx.x;
    int split = blk & (SPLIT - 1);
    int bp    = blk >> 4;
    int b     = bp / 3, plane = bp - 3 * b;
    for (int i = threadIdx.x; i < NBINS; i += 1024) hist[i] = 0u;
    __syncthreads();
    const unsigned* src = (const unsigned*)(bins + ((size_t)plane * NB + b) * NPTS
                                                 + (size_t)split * TILE);
    for (int j = threadIdx.x; j < TILE / 2; j += 1024) {
        unsigned u = src[j];
        atomicAdd(&hist[u & 0xffffu], 1u);
        atomicAdd(&hist[u >> 16], 1u);
    }
    __syncthreads();
    unsigned* dst = tot + (size_t)bp * NBINS;
    for (int i = threadIdx.x; i < NBINS; i += 1024) {
        unsigned v = hist[i];
        if (v) atomicAdd(&dst[i], v);
    }
}

// Per-bp exclusive scan of tot -> cur. 24 blocks x 1024 thr x 16 bins.
__global__ __launch_bounds__(1024) void scan_kernel(
    const unsigned* __restrict__ tot, unsigned* __restrict__ cur) {
    __shared__ unsigned tsum[1024];
    int bp = blockIdx.x, t = threadIdx.x;
    const unsigned* tp = tot + (size_t)bp * NBINS;
    int base = t * 16;
    unsigned c[16], v[16];
    const uint4* tp4 = (const uint4*)(tp + base);
#pragma unroll
    for (int q = 0; q < 4; ++q) {
        uint4 u = tp4[q];
        c[4 * q + 0] = u.x; c[4 * q + 1] = u.y;
        c[4 * q + 2] = u.z; c[4 * q + 3] = u.w;
    }
    unsigned run = 0;
#pragma unroll
    for (int k = 0; k < 16; ++k) { v[k] = run; run += c[k]; }
    tsum[t] = run;
    __syncthreads();
    for (int o = 1; o < 1024; o <<= 1) {           // Hillis-Steele inclusive
        unsigned a = (t >= o) ? tsum[t - o] : 0u;
        __syncthreads();
        tsum[t] += a;
        __syncthreads();
    }
    unsigned tb = (t > 0) ? tsum[t - 1] : 0u;
    unsigned* cp = cur + (size_t)bp * NBINS;
#pragma unroll
    for (int k = 0; k < 16; ++k) cp[base + k] = tb + v[k];
}

// Bin-sorted point ids via global atomic cursors. Within-bin order is
// nondeterministic (fine for a mean). Afterwards cur == inclusive scan.
__global__ __launch_bounds__(1024) void reorder_kernel(
    const unsigned short* __restrict__ bins, unsigned* __restrict__ cur,
    unsigned* __restrict__ S) {
    int blk   = blockIdx.x;
    int split = blk & (SPLIT - 1);
    int bp    = blk >> 4;
    int b     = bp / 3, plane = bp - 3 * b;
    const unsigned* src = (const unsigned*)(bins + ((size_t)plane * NB + b) * NPTS
                                                 + (size_t)split * TILE);
    unsigned nbase = (unsigned)(split * TILE);
    unsigned* curp = cur + (size_t)bp * NBINS;
    unsigned* Sp   = S + (size_t)bp * NPTS;
    for (int j = threadIdx.x; j < TILE / 2; j += 1024) {
        unsigned u  = src[j];
        unsigned p0 = atomicAdd(&curp[u & 0xffffu], 1u);
        Sp[p0] = nbase + 2 * j;
        unsigned p1 = atomicAdd(&curp[u >> 16], 1u);
        Sp[p1] = nbase + 2 * j + 1;
    }
}

// feat (b, C, N) fp32 -> ftT (b, n, c) bf16 (RNE). One point = 64 B line.
constexpr int TTILES = (NPTS + 255) / 256;   // 782
__global__ __launch_bounds__(256) void transpose_kernel(
    const float* __restrict__ feat, unsigned short* __restrict__ ftT) {
    int b = blockIdx.x / TTILES;
    int n = (blockIdx.x % TTILES) * 256 + threadIdx.x;
    if (n >= NPTS) return;
    const float* fb = feat + (size_t)b * NC * NPTS + n;
    unsigned pk[16];
#pragma unroll
    for (int c = 0; c < 16; ++c) {
        unsigned u0 = __float_as_uint(fb[(size_t)(2 * c) * NPTS]);
        unsigned u1 = __float_as_uint(fb[(size_t)(2 * c + 1) * NPTS]);
        unsigned r0 = (u0 + 0x7fffu + ((u0 >> 16) & 1u)) >> 16;   // bf16 RNE
        unsigned r1 = (u1 + 0x7fffu + ((u1 >> 16) & 1u)) >> 16;
        pk[c] = r0 | (r1 << 16);
    }
    uint4* dst = (uint4*)(ftT + ((size_t)b * NPTS + n) * NC);
#pragma unroll
    for (int q = 0; q < 4; ++q)
        dst[q] = make_uint4(pk[4 * q], pk[4 * q + 1], pk[4 * q + 2], pk[4 * q + 3]);
}

__device__ __forceinline__ void accum8(float* acc, uint4 v) {
    acc[0] += __uint_as_float(v.x << 16);
    acc[1] += __uint_as_float(v.x & 0xffff0000u);
    acc[2] += __uint_as_float(v.y << 16);
    acc[3] += __uint_as_float(v.y & 0xffff0000u);
    acc[4] += __uint_as_float(v.z << 16);
    acc[5] += __uint_as_float(v.z & 0xffff0000u);
    acc[6] += __uint_as_float(v.w << 16);
    acc[7] += __uint_as_float(v.w & 0xffff0000u);
}

// One LANE per bin: each lane accumulates all 32 channels in registers.
// Sequential depth per lane ~= bin size (~12), and a wave keeps up to
// 64 lanes x 8 dwordx4 loads in flight -> MLP-bound no more.
// Stores: consecutive lanes = consecutive bins -> coalesced per channel.
__global__ __launch_bounds__(256) void gather_kernel(
    const unsigned* __restrict__ cur, const unsigned* __restrict__ S,
    const unsigned short* __restrict__ ftT, float* __restrict__ out) {
    int bp  = blockIdx.x >> 6;                    // 64 blocks per bp
    int bin = ((blockIdx.x & 63) << 8) | threadIdx.x;
    int b   = bp / 3;
    const unsigned* cp = cur + (size_t)bp * NBINS;  // inclusive scan now
    unsigned e = cp[bin];
    unsigned s = (bin > 0) ? cp[bin - 1] : 0u;
    const unsigned* Sp = S + (size_t)bp * NPTS;
    const unsigned short* fb = ftT + (size_t)b * NPTS * NC;
    float acc[NC];
#pragma unroll
    for (int c = 0; c < NC; ++c) acc[c] = 0.0f;
    unsigned p = s;
    for (; p + 2 <= e; p += 2) {
        unsigned n0 = Sp[p], n1 = Sp[p + 1];
        const uint4* q0 = (const uint4*)(fb + (size_t)n0 * NC);
        const uint4* q1 = (const uint4*)(fb + (size_t)n1 * NC);
        uint4 a0 = q0[0], a1 = q0[1], a2 = q0[2], a3 = q0[3];
        uint4 b0 = q1[0], b1 = q1[1], b2 = q1[2], b3 = q1[3];
        accum8(acc +  0, a0); accum8(acc +  8, a1);
        accum8(acc + 16, a2); accum8(acc + 24, a3);
        accum8(acc +  0, b0); accum8(acc +  8, b1);
        accum8(acc + 16, b2); accum8(acc + 24, b3);
    }
    if (p < e) {
        unsigned n0 = Sp[p];
        const uint4* q0 = (const uint4*)(fb + (size_t)n0 * NC);
        uint4 a0 = q0[0], a1 = q0[1], a2 = q0[2], a3 = q0[3];
        accum8(acc +  0, a0); accum8(acc +  8, a1);
        accum8(acc + 16, a2); accum8(acc + 24, a3);
    }
    float inv = 1.0f / fmaxf((float)(e - s), 1.0f);   // empty bins -> 0
    float* ob = out + (size_t)bp * NC * NBINS + bin;
#pragma unroll
    for (int c = 0; c < NC; ++c) ob[(size_t)c * NBINS] = acc[c] * inv;
}

// ---------- fallback (round-3 verified path; needs only bins + cnt) ----------
constexpr int CHUNKS = NPTS / 8;
__global__ __launch_bounds__(1024) void count_fb_kernel(
    const unsigned short* __restrict__ bins, unsigned* __restrict__ cnt) {
    __shared__ unsigned hist[NBINS];
    int blk   = blockIdx.x;
    int split = blk & (SPLIT - 1);
    int bp    = blk >> 4;
    int b     = bp / 3, plane = bp - 3 * b;
    for (int i = threadIdx.x; i < NBINS; i += 1024) hist[i] = 0u;
    __syncthreads();
    const unsigned short* src = bins + ((size_t)plane * NB + b) * NPTS
                                     + (size_t)split * TILE;
    for (int n = threadIdx.x; n < TILE; n += 1024) atomicAdd(&hist[src[n]], 1u);
    __syncthreads();
    unsigned* dst = cnt + (size_t)bp * NBINS;
    for (int i = threadIdx.x; i < NBINS; i += 1024) {
        unsigned v = hist[i];
        if (v) atomicAdd(&dst[i], v);
    }
}
__global__ __launch_bounds__(1024) void scatter_kernel(
    const unsigned short* __restrict__ bins, const float* __restrict__ feat,
    const unsigned* __restrict__ cnt, float* __restrict__ out) {
    __shared__ float hist[NBINS];
    int blk = blockIdx.x, b = blk / 96;
    int rem = blk - b * 96, plane = rem >> 5, ch = rem & 31;
    for (int i = threadIdx.x; i < NBINS; i += 1024) hist[i] = 0.0f;
    __syncthreads();
    const uint4*  bp4 = (const uint4*)(bins + ((size_t)plane * NB + b) * NPTS);
    const float4* fp4 = (const float4*)(feat + ((size_t)b * NC + ch) * NPTS);
    for (int p = threadIdx.x; p < CHUNKS; p += 1024) {
        uint4 bb = bp4[p];
        float4 f0 = fp4[2 * p], f1 = fp4[2 * p + 1];
        atomicAdd(&hist[bb.x & 0xffffu], f0.x);
        atomicAdd(&hist[bb.x >> 16],     f0.y);
        atomicAdd(&hist[bb.y & 0xffffu], f0.z);
        atomicAdd(&hist[bb.y >> 16],     f0.w);
        atomicAdd(&hist[bb.z & 0xffffu], f1.x);
        atomicAdd(&hist[bb.z >> 16],     f1.y);
        atomicAdd(&hist[bb.w & 0xffffu], f1.z);
        atomicAdd(&hist[bb.w >> 16],     f1.w);
    }
    __syncthreads();
    const unsigned* cb = cnt + (size_t)(b * 3 + plane) * NBINS;
    float* ob = out + (((size_t)b * 3 + plane) * NC + ch) * (size_t)NBINS;
    for (int i = threadIdx.x; i < NBINS; i += 1024)
        ob[i] = hist[i] / fmaxf((float)cb[i], 1.0f);
}

extern "C" void kernel_launch(void* const* d_in, const int* in_sizes, int n_in,
                              void* d_out, int out_size, void* d_ws, size_t ws_size,
                              hipStream_t stream) {
    const float* xyz  = (const float*)d_in[0];         // (B, N, 3)
    const float* feat = (const float*)d_in[1];         // (B, C, N)
    float* out = (float*)d_out;                        // (B, 3, C, R, R)
    char* ws = (char*)d_ws;
    unsigned short* bins = (unsigned short*)ws;

    int total_pts = NB * NPTS;
    bin_kernel<<<(total_pts + 255) / 256, 256, 0, stream>>>(xyz, bins);

    if (ws_size >= WS_NEED) {
        unsigned* tot = (unsigned*)(ws + OFF_TOT);
        unsigned* cur = (unsigned*)(ws + OFF_CUR);
        unsigned* S   = (unsigned*)(ws + OFF_S);
        unsigned short* ftT = (unsigned short*)ws;     // overlays bins/tot
        hipMemsetAsync(tot, 0, (size_t)NB * 3 * NBINS * sizeof(unsigned), stream);
        count_kernel<<<NB * 3 * SPLIT, 1024, 0, stream>>>(bins, tot);
        scan_kernel<<<NB * 3, 1024, 0, stream>>>(tot, cur);
        reorder_kernel<<<NB * 3 * SPLIT, 1024, 0, stream>>>(bins, cur, S);
        transpose_kernel<<<NB * TTILES, 256, 0, stream>>>(feat, ftT);  // after reorder!
        gather_kernel<<<NB * 3 * 64, 256, 0, stream>>>(cur, S, ftT, out);
    } else {
        unsigned* cnt = (unsigned*)(ws + OFF_TOT);
        hipMemsetAsync(cnt, 0, (size_t)NB * 3 * NBINS * sizeof(unsigned), stream);
        count_fb_kernel<<<NB * 3 * SPLIT, 1024, 0, stream>>>(bins, cnt);
        scatter_kernel<<<NB * 3 * NC, 1024, 0, stream>>>(bins, feat, cnt, out);
    }
}